// Round 1
// baseline (765.363 us; speedup 1.0000x reference)
//
#include <hip/hip_runtime.h>
#include <math.h>

#define F 64

// ---------------- CSR build ----------------

__global__ __launch_bounds__(256) void k_init_counts(int* __restrict__ counts, int n) {
  int i = blockIdx.x * 256 + threadIdx.x;
  if (i < n) counts[i] = 1;  // reserve slot 0 of each row for the self-loop
}

__global__ __launch_bounds__(256) void k_hist(const int* __restrict__ dst, int* __restrict__ counts, int e) {
  int i = blockIdx.x * 256 + threadIdx.x;
  if (i < e) atomicAdd(&counts[dst[i]], 1);
}

// per-256-block exclusive scan; block totals to bsums
__global__ __launch_bounds__(256) void k_scan1(const int* __restrict__ counts, int* __restrict__ offs,
                                               int* __restrict__ bsums, int n) {
  int tid = threadIdx.x, lane = tid & 63, wv = tid >> 6;
  int i = blockIdx.x * 256 + tid;
  int v = (i < n) ? counts[i] : 0;
  int x = v;
  #pragma unroll
  for (int o = 1; o <= 32; o <<= 1) { int y = __shfl_up(x, o); if (lane >= o) x += y; }
  __shared__ int wsum[4];
  if (lane == 63) wsum[wv] = x;
  __syncthreads();
  int add = 0;
  for (int w = 0; w < wv; w++) add += wsum[w];
  int incl = x + add;
  if (i < n) offs[i] = incl - v;
  if (tid == 255) bsums[blockIdx.x] = incl;
}

// single-block exclusive scan of block sums (nb <= 1024)
__global__ __launch_bounds__(256) void k_scan2(int* __restrict__ bs, int nb) {
  __shared__ int wsum[4];
  __shared__ int carry_sh;
  int tid = threadIdx.x, lane = tid & 63, wv = tid >> 6;
  if (tid == 0) carry_sh = 0;
  __syncthreads();
  for (int base = 0; base < nb; base += 256) {
    int i = base + tid;
    int v = (i < nb) ? bs[i] : 0;
    int x = v;
    #pragma unroll
    for (int o = 1; o <= 32; o <<= 1) { int y = __shfl_up(x, o); if (lane >= o) x += y; }
    if (lane == 63) wsum[wv] = x;
    __syncthreads();
    int add = 0;
    for (int w = 0; w < wv; w++) add += wsum[w];
    int incl = x + add;
    int carry = carry_sh;
    if (i < nb) bs[i] = incl - v + carry;
    __syncthreads();
    if (tid == 255) carry_sh = carry + incl;
    __syncthreads();
  }
}

__global__ __launch_bounds__(256) void k_scan3(int* __restrict__ offs, const int* __restrict__ bsums,
                                               int n, int total) {
  int i = blockIdx.x * 256 + threadIdx.x;
  if (i < n) offs[i] += bsums[i >> 8];
  if (i == 0) offs[n] = total;
}

__global__ __launch_bounds__(256) void k_selfloop(const int* __restrict__ offs, int* __restrict__ ssrc,
                                                  int* __restrict__ cursor, int n) {
  int i = blockIdx.x * 256 + threadIdx.x;
  if (i < n) { int p = offs[i]; ssrc[p] = i; cursor[i] = p + 1; }
}

__global__ __launch_bounds__(256) void k_scatter(const int* __restrict__ esrc, const int* __restrict__ edst,
                                                 int* __restrict__ cursor, int* __restrict__ ssrc, int e) {
  int i = blockIdx.x * 256 + threadIdx.x;
  if (i < e) {
    int d = edst[i];
    int p = atomicAdd(&cursor[d], 1);
    ssrc[p] = esrc[i];
  }
}

// ---------------- GEMM h = in @ W (64x64), fused al_src/al_dst ----------------
// wave-per-row, lane = output channel, W column held in registers,
// x rows staged in LDS and read as wave-uniform broadcast float4.
__global__ __launch_bounds__(256) void k_gemm(const float* __restrict__ in, const float* __restrict__ W,
                                              const float* __restrict__ avs, const float* __restrict__ avd,
                                              float* __restrict__ hg, float* __restrict__ als,
                                              float* __restrict__ ald, int n) {
  __shared__ float4 Xsh[64 * 16];  // 64 rows x 64 f32 = 16 KB
  int tid = threadIdx.x, lane = tid & 63, wv = tid >> 6;
  float wreg[F];
  #pragma unroll
  for (int k = 0; k < F; k++) wreg[k] = W[k * F + lane];
  float as = avs[lane], ad = avd[lane];
  const float4* in4 = (const float4*)in;
  int nchunks = n >> 6;
  for (int chunk = blockIdx.x; chunk < nchunks; chunk += gridDim.x) {
    int r0 = chunk << 6;
    __syncthreads();
    #pragma unroll
    for (int i = 0; i < 4; i++) Xsh[i * 256 + tid] = in4[(size_t)r0 * 16 + i * 256 + tid];
    __syncthreads();
    int rl0 = wv * 16;
    for (int rl = rl0; rl < rl0 + 16; rl++) {
      float acc = 0.f;
      #pragma unroll
      for (int k4 = 0; k4 < 16; k4++) {
        float4 xk = Xsh[rl * 16 + k4];
        acc = fmaf(xk.x, wreg[k4 * 4 + 0], acc);
        acc = fmaf(xk.y, wreg[k4 * 4 + 1], acc);
        acc = fmaf(xk.z, wreg[k4 * 4 + 2], acc);
        acc = fmaf(xk.w, wreg[k4 * 4 + 3], acc);
      }
      int r = r0 + rl;
      hg[(size_t)r * F + lane] = acc;
      float ps = acc * as, pd = acc * ad;
      #pragma unroll
      for (int o = 32; o >= 1; o >>= 1) { ps += __shfl_xor(ps, o); pd += __shfl_xor(pd, o); }
      if (lane == 0) { als[r] = ps; ald[r] = pd; }
    }
  }
}

// ---------------- fused softmax + aggregation, wave per dst node ----------------
__global__ __launch_bounds__(256) void k_agg(const int* __restrict__ offs, const int* __restrict__ ssrc,
                                             const float* __restrict__ hg, const float* __restrict__ als,
                                             const float* __restrict__ ald, const float* __restrict__ bias,
                                             float* __restrict__ outp, int n) {
  int tid = threadIdx.x, lane = tid & 63, wv = tid >> 6;
  int grp = lane >> 4, lq = lane & 15;
  int node = blockIdx.x * 4 + wv;
  if (node >= n) return;
  const float4* hg4 = (const float4*)hg;
  float4 b4 = ((const float4*)bias)[lq];
  int beg = offs[node], end = offs[node + 1];
  int deg = end - beg;
  float aldv = ald[node];
  float m = -INFINITY, s = 0.f;
  float4 acc = make_float4(0.f, 0.f, 0.f, 0.f);
  for (int cbeg = 0; cbeg < deg; cbeg += 64) {
    int nvalid = min(64, deg - cbeg);
    float e = -INFINITY;
    int srcl = 0;
    if (lane < nvalid) {
      srcl = ssrc[beg + cbeg + lane];
      float t = als[srcl] + aldv;
      e = (t >= 0.f) ? t : 0.2f * t;   // leaky_relu 0.2
    }
    float cm = e;
    #pragma unroll
    for (int o = 32; o >= 1; o >>= 1) cm = fmaxf(cm, __shfl_xor(cm, o));
    float nm = fmaxf(m, cm);                 // chunk has >=1 valid edge -> finite
    float scale = __expf(m - nm);            // first chunk: exp(-inf)=0, s/acc are 0 anyway
    float ex = __expf(e - nm);               // invalid lanes: exp(-inf)=0
    float cs = ex;
    #pragma unroll
    for (int o = 32; o >= 1; o >>= 1) cs += __shfl_xor(cs, o);
    s = s * scale + cs;
    acc.x *= scale; acc.y *= scale; acc.z *= scale; acc.w *= scale;
    // 4 edges in flight: group g handles edge j4*4+g; 16 lanes x float4 = one 256B row
    int iters = (nvalid + 3) >> 2;
    for (int j4 = 0; j4 < iters; j4++) {
      int j = (j4 << 2) + grp;               // j <= 63 always
      float w = __shfl(ex, j);
      int sj = __shfl(srcl, j);
      if (w != 0.f) {
        float4 hrow = hg4[(size_t)sj * 16 + lq];
        acc.x = fmaf(w, hrow.x, acc.x);
        acc.y = fmaf(w, hrow.y, acc.y);
        acc.z = fmaf(w, hrow.z, acc.z);
        acc.w = fmaf(w, hrow.w, acc.w);
      }
    }
    m = nm;
  }
  float inv = 1.f / (s + 1e-16f);
  // sum the 4 edge-groups (lanes l, l^16, l^32, l^48 hold the same channels)
  #pragma unroll
  for (int o = 16; o <= 32; o <<= 1) {
    acc.x += __shfl_xor(acc.x, o);
    acc.y += __shfl_xor(acc.y, o);
    acc.z += __shfl_xor(acc.z, o);
    acc.w += __shfl_xor(acc.w, o);
  }
  if (lane < 16) {
    float4 r;
    r.x = fmaxf(fmaf(acc.x, inv, b4.x), 0.f);
    r.y = fmaxf(fmaf(acc.y, inv, b4.y), 0.f);
    r.z = fmaxf(fmaf(acc.z, inv, b4.z), 0.f);
    r.w = fmaxf(fmaf(acc.w, inv, b4.w), 0.f);
    ((float4*)outp)[(size_t)node * 16 + lq] = r;
  }
}

// ---------------- final readout: out[g] = h[g*1280 .. +1280) . W_out + b ----------------
__global__ __launch_bounds__(256) void k_final(const float* __restrict__ h, const float* __restrict__ Wout,
                                               const float* __restrict__ bout, float* __restrict__ out,
                                               int ng) {
  int tid = threadIdx.x, lane = tid & 63, wv = tid >> 6;
  int g = blockIdx.x * 4 + wv;
  if (g >= ng) return;
  const float4* h4 = (const float4*)h + (size_t)g * 320;
  const float4* w4 = (const float4*)Wout;
  float sacc = 0.f;
  #pragma unroll
  for (int k = 0; k < 5; k++) {   // 320 float4 / 64 lanes
    float4 a = h4[k * 64 + lane];
    float4 b = w4[k * 64 + lane];
    sacc += a.x * b.x + a.y * b.y + a.z * b.z + a.w * b.w;
  }
  #pragma unroll
  for (int o = 32; o >= 1; o >>= 1) sacc += __shfl_xor(sacc, o);
  if (lane == 0) out[g] = sacc + bout[0];
}

// ---------------- launch ----------------
extern "C" void kernel_launch(void* const* d_in, const int* in_sizes, int n_in,
                              void* d_out, int out_size, void* d_ws, size_t ws_size,
                              hipStream_t stream) {
  const float* x   = (const float*)d_in[0];
  const int*   ei  = (const int*)d_in[1];
  const float* W1  = (const float*)d_in[2];
  const float* as1 = (const float*)d_in[3];
  const float* ad1 = (const float*)d_in[4];
  const float* b1  = (const float*)d_in[5];
  const float* W2  = (const float*)d_in[6];
  const float* as2 = (const float*)d_in[7];
  const float* ad2 = (const float*)d_in[8];
  const float* b2  = (const float*)d_in[9];
  const float* Wo  = (const float*)d_in[10];
  const float* bo  = (const float*)d_in[11];
  float* out = (float*)d_out;

  const int N = in_sizes[0] / F;
  const int E = in_sizes[1] / 2;
  const int* esrc = ei;
  const int* edst = ei + E;

  size_t off = 0;
  auto alloc = [&](size_t bytes) -> void* {
    void* p = (char*)d_ws + off;
    off += (bytes + 255) & ~(size_t)255;
    return p;
  };
  float* A    = (float*)alloc((size_t)N * F * 4);   // agg outputs (layer inputs)
  float* B    = (float*)alloc((size_t)N * F * 4);   // gemm outputs
  float* als  = (float*)alloc((size_t)N * 4);
  float* ald  = (float*)alloc((size_t)N * 4);
  int* counts = (int*)alloc((size_t)N * 4);         // histogram, then scatter cursor
  int* offs   = (int*)alloc((size_t)(N + 1) * 4);
  int* bsums  = (int*)alloc(4096);
  int* ssrc   = (int*)alloc((size_t)(E + N) * 4);   // CSR src lists
  (void)ws_size; (void)n_in; (void)out_size;

  int gN = (N + 255) / 256;
  int gE = (E + 255) / 256;

  // CSR build (dst-sorted, self-loop at row head)
  k_init_counts<<<gN, 256, 0, stream>>>(counts, N);
  k_hist<<<gE, 256, 0, stream>>>(edst, counts, E);
  k_scan1<<<gN, 256, 0, stream>>>(counts, offs, bsums, N);
  k_scan2<<<1, 256, 0, stream>>>(bsums, gN);
  k_scan3<<<gN, 256, 0, stream>>>(offs, bsums, N, N + E);
  k_selfloop<<<gN, 256, 0, stream>>>(offs, ssrc, counts, N);
  k_scatter<<<gE, 256, 0, stream>>>(esrc, edst, counts, ssrc, E);

  // layer 1
  k_gemm<<<640, 256, 0, stream>>>(x, W1, as1, ad1, B, als, ald, N);
  k_agg<<<(N + 3) / 4, 256, 0, stream>>>(offs, ssrc, B, als, ald, b1, A, N);
  // layer 2
  k_gemm<<<640, 256, 0, stream>>>(A, W2, as2, ad2, B, als, ald, N);
  k_agg<<<(N + 3) / 4, 256, 0, stream>>>(offs, ssrc, B, als, ald, b2, A, N);
  // readout
  int NG = N / 20;
  k_final<<<(NG + 3) / 4, 256, 0, stream>>>(A, Wo, bo, out, NG);
}

// Round 2
// 521.789 us; speedup vs baseline: 1.4668x; 1.4668x over previous
//
#include <hip/hip_runtime.h>
#include <math.h>

#define F 64
#define NPB 160        // nodes per bucket
#define STAGE_CAP 6304 // staged CSR entries per bucket (mean ~2720, +60 sigma)

// ---------------- bucketed CSR build ----------------

// per-block LDS histogram of dst buckets; cntT[b*NBLK + k] = count of block k's edges in bucket b
__global__ __launch_bounds__(256) void k_bin_count(const int* __restrict__ edst, int* __restrict__ cntT,
                                                   int e, int ch, int nblk, int nb) {
  __shared__ int h[1024];
  int k = blockIdx.x, tid = threadIdx.x;
  for (int i = tid; i < nb; i += 256) h[i] = 0;
  __syncthreads();
  int beg = k * ch, end = min(e, beg + ch);
  for (int i = beg + tid; i < end; i += 256) atomicAdd(&h[edst[i] / NPB], 1);
  __syncthreads();
  for (int b = tid; b < nb; b += 256) cntT[b * nblk + k] = h[b];
}

// per-256-block exclusive scan; block totals to bsums
__global__ __launch_bounds__(256) void k_scan1(const int* __restrict__ counts, int* __restrict__ offs,
                                               int* __restrict__ bsums, int n) {
  int tid = threadIdx.x, lane = tid & 63, wv = tid >> 6;
  int i = blockIdx.x * 256 + tid;
  int v = (i < n) ? counts[i] : 0;
  int x = v;
  #pragma unroll
  for (int o = 1; o <= 32; o <<= 1) { int y = __shfl_up(x, o); if (lane >= o) x += y; }
  __shared__ int wsum[4];
  if (lane == 63) wsum[wv] = x;
  __syncthreads();
  int add = 0;
  for (int w = 0; w < wv; w++) add += wsum[w];
  int incl = x + add;
  if (i < n) offs[i] = incl - v;
  if (tid == 255) bsums[blockIdx.x] = incl;
}

// single-block exclusive scan of block sums
__global__ __launch_bounds__(256) void k_scan2(int* __restrict__ bs, int nb) {
  __shared__ int wsum[4];
  __shared__ int carry_sh;
  int tid = threadIdx.x, lane = tid & 63, wv = tid >> 6;
  if (tid == 0) carry_sh = 0;
  __syncthreads();
  for (int base = 0; base < nb; base += 256) {
    int i = base + tid;
    int v = (i < nb) ? bs[i] : 0;
    int x = v;
    #pragma unroll
    for (int o = 1; o <= 32; o <<= 1) { int y = __shfl_up(x, o); if (lane >= o) x += y; }
    if (lane == 63) wsum[wv] = x;
    __syncthreads();
    int add = 0;
    for (int w = 0; w < wv; w++) add += wsum[w];
    int incl = x + add;
    int carry = carry_sh;
    if (i < nb) bs[i] = incl - v + carry;
    __syncthreads();
    if (tid == 255) carry_sh = carry + incl;
    __syncthreads();
  }
}

__global__ __launch_bounds__(256) void k_scan3(int* __restrict__ offs, const int* __restrict__ bsums,
                                               int n, int total) {
  int i = blockIdx.x * 256 + threadIdx.x;
  if (i < n) offs[i] += bsums[i >> 8];
  if (i == 0) offs[n] = total;
}

// scatter edges into bucket-contiguous slices; packed (local_dst<<24)|src
__global__ __launch_bounds__(256) void k_bin_scatter(const int* __restrict__ esrc, const int* __restrict__ edst,
                                                     const int* __restrict__ posT, unsigned int* __restrict__ binned,
                                                     int e, int ch, int nblk, int nb) {
  __shared__ int cur[1024];
  int k = blockIdx.x, tid = threadIdx.x;
  for (int b = tid; b < nb; b += 256) cur[b] = posT[b * nblk + k];
  __syncthreads();
  int beg = k * ch, end = min(e, beg + ch);
  for (int i = beg + tid; i < end; i += 256) {
    int d = edst[i];
    int b = d / NPB;
    unsigned int ld = (unsigned int)(d - b * NPB);
    int p = atomicAdd(&cur[b], 1);
    binned[p] = (unsigned int)esrc[i] | (ld << 24);
  }
}

// one block per bucket: build CSR rows (self-loop at row head) via LDS staging, emit offs
__global__ __launch_bounds__(256) void k_bucket_csr(const unsigned int* __restrict__ binned,
                                                    const int* __restrict__ posT,
                                                    int* __restrict__ ssrc, int* __restrict__ offs,
                                                    int n, int nblk, int nb, int e) {
  __shared__ int ncnt[NPB];
  __shared__ int noff[NPB];
  __shared__ int cur[NPB];
  __shared__ int sc[256];
  __shared__ int stage[STAGE_CAP];
  int b = blockIdx.x, tid = threadIdx.x;
  int node0 = b * NPB;
  int nn = min(NPB, n - node0);
  int ebeg = posT[b * nblk];
  int eend = posT[(b + 1) * nblk];  // sentinel posT[nb*nblk]=e written by k_scan3
  int ecnt = eend - ebeg;
  for (int i = tid; i < NPB; i += 256) ncnt[i] = 0;
  __syncthreads();
  for (int i = tid; i < ecnt; i += 256) { unsigned int v = binned[ebeg + i]; atomicAdd(&ncnt[v >> 24], 1); }
  __syncthreads();
  // inclusive Hillis-Steele scan over 256 slots of (ncnt+1 self-loop)
  int x = (tid < nn) ? ncnt[tid] + 1 : 0;
  sc[tid] = x;
  __syncthreads();
  #pragma unroll
  for (int o = 1; o < 256; o <<= 1) {
    int y = (tid >= o) ? sc[tid - o] : 0;
    __syncthreads();
    sc[tid] += y;
    __syncthreads();
  }
  if (tid < nn) noff[tid] = sc[tid] - x;  // exclusive
  __syncthreads();
  int tot = ecnt + nn;
  int outbase = ebeg + node0;  // edges before bucket + self-loops before bucket
  bool staged = (tot <= STAGE_CAP);
  if (tid < nn) {
    cur[tid] = noff[tid] + 1;
    offs[node0 + tid] = outbase + noff[tid];
    if (staged) stage[noff[tid]] = node0 + tid;
    else        ssrc[outbase + noff[tid]] = node0 + tid;
  }
  __syncthreads();
  if (staged) {
    for (int i = tid; i < ecnt; i += 256) {
      unsigned int v = binned[ebeg + i];
      int p = atomicAdd(&cur[v >> 24], 1);
      stage[p] = (int)(v & 0xFFFFFFu);
    }
    __syncthreads();
    for (int i = tid; i < tot; i += 256) ssrc[outbase + i] = stage[i];
  } else {
    for (int i = tid; i < ecnt; i += 256) {
      unsigned int v = binned[ebeg + i];
      int p = atomicAdd(&cur[v >> 24], 1);
      ssrc[outbase + p] = (int)(v & 0xFFFFFFu);
    }
  }
  if (b == 0 && tid == 0) offs[n] = e + n;
}

// ---------------- GEMM h = in @ W (64x64), fused al_src/al_dst ----------------
__global__ __launch_bounds__(256) void k_gemm(const float* __restrict__ in, const float* __restrict__ W,
                                              const float* __restrict__ avs, const float* __restrict__ avd,
                                              float* __restrict__ hg, float* __restrict__ als,
                                              float* __restrict__ ald, int n) {
  __shared__ float4 Xsh[64 * 16];  // 64 rows x 64 f32 = 16 KB
  int tid = threadIdx.x, lane = tid & 63, wv = tid >> 6;
  float wreg[F];
  #pragma unroll
  for (int k = 0; k < F; k++) wreg[k] = W[k * F + lane];
  float as = avs[lane], ad = avd[lane];
  const float4* in4 = (const float4*)in;
  int nchunks = n >> 6;
  for (int chunk = blockIdx.x; chunk < nchunks; chunk += gridDim.x) {
    int r0 = chunk << 6;
    __syncthreads();
    #pragma unroll
    for (int i = 0; i < 4; i++) Xsh[i * 256 + tid] = in4[(size_t)r0 * 16 + i * 256 + tid];
    __syncthreads();
    int rl0 = wv * 16;
    for (int rl = rl0; rl < rl0 + 16; rl++) {
      float acc = 0.f;
      #pragma unroll
      for (int k4 = 0; k4 < 16; k4++) {
        float4 xk = Xsh[rl * 16 + k4];
        acc = fmaf(xk.x, wreg[k4 * 4 + 0], acc);
        acc = fmaf(xk.y, wreg[k4 * 4 + 1], acc);
        acc = fmaf(xk.z, wreg[k4 * 4 + 2], acc);
        acc = fmaf(xk.w, wreg[k4 * 4 + 3], acc);
      }
      int r = r0 + rl;
      hg[(size_t)r * F + lane] = acc;
      float ps = acc * as, pd = acc * ad;
      #pragma unroll
      for (int o = 32; o >= 1; o >>= 1) { ps += __shfl_xor(ps, o); pd += __shfl_xor(pd, o); }
      if (lane == 0) { als[r] = ps; ald[r] = pd; }
    }
  }
}

// ---------------- fused softmax + aggregation, wave per dst node ----------------
__global__ __launch_bounds__(256) void k_agg(const int* __restrict__ offs, const int* __restrict__ ssrc,
                                             const float* __restrict__ hg, const float* __restrict__ als,
                                             const float* __restrict__ ald, const float* __restrict__ bias,
                                             float* __restrict__ outp, int n) {
  int tid = threadIdx.x, lane = tid & 63, wv = tid >> 6;
  int grp = lane >> 4, lq = lane & 15;
  int node = blockIdx.x * 4 + wv;
  if (node >= n) return;
  const float4* hg4 = (const float4*)hg;
  float4 b4 = ((const float4*)bias)[lq];
  int beg = offs[node], end = offs[node + 1];
  int deg = end - beg;
  float aldv = ald[node];
  float m = -INFINITY, s = 0.f;
  float4 acc = make_float4(0.f, 0.f, 0.f, 0.f);
  for (int cbeg = 0; cbeg < deg; cbeg += 64) {
    int nvalid = min(64, deg - cbeg);
    float e = -INFINITY;
    int srcl = 0;
    if (lane < nvalid) {
      srcl = ssrc[beg + cbeg + lane];
      float t = als[srcl] + aldv;
      e = (t >= 0.f) ? t : 0.2f * t;   // leaky_relu 0.2
    }
    float cm = e;
    #pragma unroll
    for (int o = 32; o >= 1; o >>= 1) cm = fmaxf(cm, __shfl_xor(cm, o));
    float nm = fmaxf(m, cm);
    float scale = __expf(m - nm);
    float ex = __expf(e - nm);
    float cs = ex;
    #pragma unroll
    for (int o = 32; o >= 1; o >>= 1) cs += __shfl_xor(cs, o);
    s = s * scale + cs;
    acc.x *= scale; acc.y *= scale; acc.z *= scale; acc.w *= scale;
    int iters = (nvalid + 3) >> 2;
    for (int j4 = 0; j4 < iters; j4++) {
      int j = (j4 << 2) + grp;
      float w = __shfl(ex, j);
      int sj = __shfl(srcl, j);
      if (w != 0.f) {
        float4 hrow = hg4[(size_t)sj * 16 + lq];
        acc.x = fmaf(w, hrow.x, acc.x);
        acc.y = fmaf(w, hrow.y, acc.y);
        acc.z = fmaf(w, hrow.z, acc.z);
        acc.w = fmaf(w, hrow.w, acc.w);
      }
    }
    m = nm;
  }
  float inv = 1.f / (s + 1e-16f);
  #pragma unroll
  for (int o = 16; o <= 32; o <<= 1) {
    acc.x += __shfl_xor(acc.x, o);
    acc.y += __shfl_xor(acc.y, o);
    acc.z += __shfl_xor(acc.z, o);
    acc.w += __shfl_xor(acc.w, o);
  }
  if (lane < 16) {
    float4 r;
    r.x = fmaxf(fmaf(acc.x, inv, b4.x), 0.f);
    r.y = fmaxf(fmaf(acc.y, inv, b4.y), 0.f);
    r.z = fmaxf(fmaf(acc.z, inv, b4.z), 0.f);
    r.w = fmaxf(fmaf(acc.w, inv, b4.w), 0.f);
    ((float4*)outp)[(size_t)node * 16 + lq] = r;
  }
}

// ---------------- final readout ----------------
__global__ __launch_bounds__(256) void k_final(const float* __restrict__ h, const float* __restrict__ Wout,
                                               const float* __restrict__ bout, float* __restrict__ out,
                                               int ng) {
  int tid = threadIdx.x, lane = tid & 63, wv = tid >> 6;
  int g = blockIdx.x * 4 + wv;
  if (g >= ng) return;
  const float4* h4 = (const float4*)h + (size_t)g * 320;
  const float4* w4 = (const float4*)Wout;
  float sacc = 0.f;
  #pragma unroll
  for (int k = 0; k < 5; k++) {
    float4 a = h4[k * 64 + lane];
    float4 b = w4[k * 64 + lane];
    sacc += a.x * b.x + a.y * b.y + a.z * b.z + a.w * b.w;
  }
  #pragma unroll
  for (int o = 32; o >= 1; o >>= 1) sacc += __shfl_xor(sacc, o);
  if (lane == 0) out[g] = sacc + bout[0];
}

// ---------------- launch ----------------
extern "C" void kernel_launch(void* const* d_in, const int* in_sizes, int n_in,
                              void* d_out, int out_size, void* d_ws, size_t ws_size,
                              hipStream_t stream) {
  const float* x   = (const float*)d_in[0];
  const int*   ei  = (const int*)d_in[1];
  const float* W1  = (const float*)d_in[2];
  const float* as1 = (const float*)d_in[3];
  const float* ad1 = (const float*)d_in[4];
  const float* b1  = (const float*)d_in[5];
  const float* W2  = (const float*)d_in[6];
  const float* as2 = (const float*)d_in[7];
  const float* ad2 = (const float*)d_in[8];
  const float* b2  = (const float*)d_in[9];
  const float* Wo  = (const float*)d_in[10];
  const float* bo  = (const float*)d_in[11];
  float* out = (float*)d_out;

  const int N = in_sizes[0] / F;
  const int E = in_sizes[1] / 2;
  const int* esrc = ei;
  const int* edst = ei + E;

  size_t off = 0;
  auto alloc = [&](size_t bytes) -> void* {
    void* p = (char*)d_ws + off;
    off += (bytes + 255) & ~(size_t)255;
    return p;
  };
  float* A    = (float*)alloc((size_t)N * F * 4);   // agg outputs; CSR scratch aliases head
  float* B    = (float*)alloc((size_t)N * F * 4);   // gemm outputs; binned[] aliases head
  float* als  = (float*)alloc((size_t)N * 4);
  float* ald  = (float*)alloc((size_t)N * 4);
  int* offs   = (int*)alloc((size_t)(N + 1) * 4);
  int* bsums  = (int*)alloc(8192);
  int* ssrc   = (int*)alloc((size_t)(E + N) * 4);   // CSR src lists
  (void)ws_size; (void)n_in; (void)out_size;

  const int NBLK = 160;                         // edge-chunk blocks
  const int NB = (N + NPB - 1) / NPB;           // buckets (1024)
  const int CH = (E + NBLK - 1) / NBLK;         // edges per block
  const int FLAT = NB * NBLK;                   // count-matrix size (163840)

  // scratch aliased into A (dead until k_agg) and B (dead until k_gemm)
  int* cntT = (int*)A;
  int* posT = (int*)((char*)A + ((size_t)FLAT * 4 + 1024));  // FLAT+1 ints
  unsigned int* binned = (unsigned int*)B;                    // E uints

  int gF = (FLAT + 255) / 256;

  // CSR build: bucketed counting sort (dst-major), self-loop at row head
  k_bin_count<<<NBLK, 256, 0, stream>>>(edst, cntT, E, CH, NBLK, NB);
  k_scan1<<<gF, 256, 0, stream>>>(cntT, posT, bsums, FLAT);
  k_scan2<<<1, 256, 0, stream>>>(bsums, gF);
  k_scan3<<<gF, 256, 0, stream>>>(posT, bsums, FLAT, E);
  k_bin_scatter<<<NBLK, 256, 0, stream>>>(esrc, edst, posT, binned, E, CH, NBLK, NB);
  k_bucket_csr<<<NB, 256, 0, stream>>>(binned, posT, ssrc, offs, N, NBLK, NB, E);

  // layer 1
  k_gemm<<<640, 256, 0, stream>>>(x, W1, as1, ad1, B, als, ald, N);
  k_agg<<<(N + 3) / 4, 256, 0, stream>>>(offs, ssrc, B, als, ald, b1, A, N);
  // layer 2
  k_gemm<<<640, 256, 0, stream>>>(A, W2, as2, ad2, B, als, ald, N);
  k_agg<<<(N + 3) / 4, 256, 0, stream>>>(offs, ssrc, B, als, ald, b2, A, N);
  // readout
  int NG = N / 20;
  k_final<<<(NG + 3) / 4, 256, 0, stream>>>(A, Wo, bo, out, NG);
}